// Round 5
// baseline (1038.475 us; speedup 1.0000x reference)
//
#include <hip/hip_runtime.h>
#include <hip/hip_bf16.h>

// Swin block: B=64, H=W=56, C=128, WS=7, SHIFT=3, NH=4, hd=32, hidden=512
// Round 5: dataflow fusion + weight-direct fragments.
//  - mlp_fused: fc1+GELU+fc2 in one kernel; hidden lives only in LDS (64x64
//    double-buffered chunks), 9 barriers/block vs ~128; saves 410 MB HBM.
//  - proj_ln: proj GEMM owns full 128-col rows (grid (1,gy)); LN2 fused into
//    epilogue via 16-lane shuffle + 1KB LDS cross-wave reduce; saves 103 MB.
//  - All GEMMs: B-fragments read DIRECTLY from global weight planes (L2-hot,
//    4 fq-lanes consume each 64B line); A staged fully upfront (K=128) at
//    conflict-free stride 132 -> zero barriers in MFMA main loops.
//  - attn + V k'-permutation pipeline unchanged from round 4.
// ws: [0,64K) btab | [64K,832K) weight planes | bufAh | bufAl | bufQK | bufV.

#define NWIN 4096
#define HB 7440    // attn per-head LDS shorts (8 banks mod 32)
#define KOFF 2568  // K section offset (4 banks mod 32)
#define VOFF 5136  // V^T section offset

typedef __attribute__((ext_vector_type(8))) short s8v;
typedef __attribute__((ext_vector_type(4))) float f4v;

__device__ __forceinline__ void split2(float v, unsigned short& h, unsigned short& l) {
    unsigned int b = __float_as_uint(v);
    h = (unsigned short)(b >> 16);                       // truncated hi
    float hf = __uint_as_float(b & 0xFFFF0000u);
    __hip_bfloat16 lo = __float2bfloat16(v - hf);        // exact residual, RNE
    l = *reinterpret_cast<unsigned short*>(&lo);
}
__device__ __forceinline__ unsigned short bfr(float v) {  // RNE bf16 bits
    __hip_bfloat16 h = __float2bfloat16(v);
    return *reinterpret_cast<unsigned short*>(&h);
}

// ---------------- weight pre-split: fp32 -> planar bf16 hi/lo (once) ----------------
// plane offsets (shorts): qkvWh 0, qkvWl 49152, outWh 98304, outWl 114688,
//                         w1h 131072, w1l 196608, w2h 262144, w2l 327680
__global__ __launch_bounds__(256) void presplit_kernel(
    const float* __restrict__ qkvw, const float* __restrict__ outw,
    const float* __restrict__ w1, const float* __restrict__ w2,
    unsigned short* __restrict__ P)
{
    int i = blockIdx.x * 256 + threadIdx.x;
    float v; unsigned short* ph; unsigned short* pl;
    if (i < 49152) {
        v = qkvw[i];
        if (i < 16384) v *= 0.17677669529663687f;   // fold 1/sqrt(32) into Q rows
        ph = P + i; pl = P + 49152 + i;
    } else if (i < 65536) {
        int j = i - 49152; v = outw[j];
        ph = P + 98304 + j; pl = P + 114688 + j;
    } else if (i < 131072) {
        int j = i - 65536; v = w1[j];
        ph = P + 131072 + j; pl = P + 196608 + j;
    } else if (i < 196608) {
        int j = i - 131072; v = w2[j];
        ph = P + 262144 + j; pl = P + 327680 + j;
    } else return;
    unsigned short h, l; split2(v, h, l);
    *ph = h; *pl = l;
}

// ---------------- LN1: fp32 shift-gather in -> hi/lo planes out ----------------
__global__ __launch_bounds__(256) void ln_kernel(
    const float* __restrict__ inF,
    const float* __restrict__ g, const float* __restrict__ bta,
    unsigned short* __restrict__ outH, unsigned short* __restrict__ outL,
    int tbase)
{
    int tid = threadIdx.x;
    int wave = tid >> 6, lane = tid & 63;
    int local = blockIdx.x * 4 + wave;
    int t = tbase + local;
    int n = t / 49, l = t - n * 49;
    int b = n >> 6, wh = (n >> 3) & 7, ww = n & 7;
    int i = l / 7, j = l - i * 7;
    int hh = wh * 7 + i, wimg = ww * 7 + j;
    int sh = (hh + 53) % 56, sw = (wimg + 53) % 56;
    const float* ip = inF + (size_t)((b * 56 + sh) * 56 + sw) * 128;
    float v0 = ip[lane], v1 = ip[lane + 64];
    float s = v0 + v1, sq = v0 * v0 + v1 * v1;
    #pragma unroll
    for (int off = 32; off > 0; off >>= 1) { s += __shfl_xor(s, off); sq += __shfl_xor(sq, off); }
    float mean = s * (1.0f / 128.0f);
    float var  = sq * (1.0f / 128.0f) - mean * mean;
    float rstd = rsqrtf(var + 1e-5f);
    float r0 = (v0 - mean) * rstd * g[lane]      + bta[lane];
    float r1 = (v1 - mean) * rstd * g[lane + 64] + bta[lane + 64];
    unsigned short h0, l0, h1, l1;
    split2(r0, h0, l0); split2(r1, h1, l1);
    size_t o = (size_t)local * 128;
    outH[o + lane] = h0; outH[o + lane + 64] = h1;
    outL[o + lane] = l0; outL[o + lane + 64] = l1;
}

// ---------------- QKV GEMM: A hi/lo upfront in LDS, W direct, 3-term ----------------
// Out: QK coalesced [M,256] (Q pre-scaled via weights/bias), V k'-scatter [win,128,64].
__global__ __launch_bounds__(256) void qkv_gemm(
    const unsigned short* __restrict__ Agh, const unsigned short* __restrict__ Agl,
    const unsigned short* __restrict__ W,     // qkvWh@0, qkvWl@49152
    const float* __restrict__ bias,
    unsigned short* __restrict__ OutQK, unsigned short* __restrict__ OutV,
    int M)
{
    __shared__ __align__(16) unsigned short Ah[64 * 132];
    __shared__ __align__(16) unsigned short Al[64 * 132];
    int tid = threadIdx.x;
    int m0 = blockIdx.y * 64, n0 = blockIdx.x * 64;
    for (int c = tid; c < 1024; c += 256) {
        int row = c >> 4, c8 = (c & 15) * 8;
        int ar = m0 + row; if (ar >= M) ar = M - 1;
        *reinterpret_cast<s8v*>(&Ah[row * 132 + c8]) =
            *reinterpret_cast<const s8v*>(Agh + (size_t)ar * 128 + c8);
        *reinterpret_cast<s8v*>(&Al[row * 132 + c8]) =
            *reinterpret_cast<const s8v*>(Agl + (size_t)ar * 128 + c8);
    }
    __syncthreads();
    int wv = tid >> 6, ln = tid & 63;
    int wm = wv & 1, wn = wv >> 1;
    int fm = ln & 15, fq = ln >> 4;
    const unsigned short* Wh = W;
    const unsigned short* Wl = W + 49152;
    f4v acc[2][2] = {};
    #pragma unroll
    for (int kk = 0; kk < 4; ++kk) {
        s8v fah[2], fal[2], fbh[2], fbl[2];
        #pragma unroll
        for (int t = 0; t < 2; ++t) {
            int ao = (wm * 32 + t * 16 + fm) * 132 + kk * 32 + fq * 8;
            fah[t] = *reinterpret_cast<const s8v*>(&Ah[ao]);
            fal[t] = *reinterpret_cast<const s8v*>(&Al[ao]);
            size_t wo = (size_t)(n0 + wn * 32 + t * 16 + fm) * 128 + kk * 32 + fq * 8;
            fbh[t] = *reinterpret_cast<const s8v*>(Wh + wo);
            fbl[t] = *reinterpret_cast<const s8v*>(Wl + wo);
        }
        #pragma unroll
        for (int tm = 0; tm < 2; ++tm)
            #pragma unroll
            for (int tn = 0; tn < 2; ++tn) {
                acc[tm][tn] = __builtin_amdgcn_mfma_f32_16x16x32_bf16(fah[tm], fbh[tn], acc[tm][tn], 0, 0, 0);
                acc[tm][tn] = __builtin_amdgcn_mfma_f32_16x16x32_bf16(fah[tm], fbl[tn], acc[tm][tn], 0, 0, 0);
                acc[tm][tn] = __builtin_amdgcn_mfma_f32_16x16x32_bf16(fal[tm], fbh[tn], acc[tm][tn], 0, 0, 0);
            }
    }
    #pragma unroll
    for (int tm = 0; tm < 2; ++tm)
        #pragma unroll
        for (int tn = 0; tn < 2; ++tn) {
            int col = n0 + wn * 32 + tn * 16 + fm;
            float bv = bias[col];
            if (col < 128) bv *= 0.17677669529663687f;
            #pragma unroll
            for (int r = 0; r < 4; ++r) {
                int m = m0 + wm * 32 + tm * 16 + fq * 4 + r;
                if (m >= M) continue;
                float v = acc[tm][tn][r] + bv;
                if (col < 256) {
                    OutQK[(size_t)m * 256 + col] = bfr(v);
                } else {
                    int dd = col - 256, hh = dd >> 5, d = dd & 31;
                    int win = m / 49, l2 = m - win * 49;
                    int kp = (l2 & 15) * 4 + (l2 >> 4);   // k' permutation
                    OutV[((size_t)win * 128 + hh * 32 + d) * 64 + kp] = bfr(v);
                }
            }
        }
}

// ---------------- bias table in MFMA C-layout: [4][64 lanes][16 (mt,nt)][4 r] ----------------
__global__ void bias_tab_kernel(const float* __restrict__ pe, float* __restrict__ tab) {
    int t = threadIdx.x;          // 256 = 4 heads x 64 lanes
    int h = t >> 6, ln = t & 63;
    int g = ln >> 4, c = ln & 15;
    for (int mt = 0; mt < 4; ++mt)
        for (int nt = 0; nt < 4; ++nt)
            for (int r = 0; r < 4; ++r) {
                int l1 = mt * 16 + g * 4 + r, l2 = nt * 16 + c;
                float b = 0.f;
                if (l1 < 49 && l2 < 49) {
                    int i1 = l1 / 7, j1 = l1 % 7, i2 = l2 / 7, j2 = l2 % 7;
                    b = pe[h * 169 + (i1 - i2 + 6) * 13 + (j1 - j2 + 6)];
                }
                tab[((h * 64 + ln) * 16 + mt * 4 + nt) * 4 + r] = b;
            }
}

// ---------------- MFMA attention (unchanged from round 4) ----------------
__global__ __launch_bounds__(256) void attn_mfma(
    const unsigned short* __restrict__ qk,
    const unsigned short* __restrict__ vt,
    const float* __restrict__ btab,
    unsigned short* __restrict__ oH)
{
    __shared__ __align__(16) unsigned short lds[4 * HB];
    int tid = threadIdx.x;
    int win = blockIdx.x;
    const unsigned short* srcqk = qk + (size_t)win * 49 * 256;
    const unsigned short* srcv  = vt + (size_t)win * 8192;

    for (int idx = tid; idx < 1568; idx += 256) {
        int l2 = idx >> 5, c8 = idx & 31;
        int d8 = c8 * 8;
        s8v v8 = *reinterpret_cast<const s8v*>(srcqk + (size_t)l2 * 256 + d8);
        int sec = d8 >> 7, dd = d8 & 127, hh = dd >> 5, kk = dd & 31;
        *reinterpret_cast<s8v*>(&lds[hh * HB + (sec ? KOFF : 0) + l2 * 40 + kk]) = v8;
    }
    for (int idx = tid; idx < 1024; idx += 256) {
        int row = idx >> 3, j = idx & 7;
        s8v v8 = *reinterpret_cast<const s8v*>(srcv + (size_t)row * 64 + j * 8);
        int hh = row >> 5, d = row & 31;
        *reinterpret_cast<s8v*>(&lds[hh * HB + VOFF + d * 72 + j * 8]) = v8;
    }
    __syncthreads();
    for (int i = tid; i < 1920; i += 256) {
        int hh = i / 480, rem = i % 480, d = rem / 15, j = rem % 15;
        lds[hh * HB + VOFF + d * 72 + (j + 1) * 4 + 3] = 0;
    }
    __syncthreads();

    int h = tid >> 6, ln = tid & 63;
    int fm = ln & 15, fq = ln >> 4;
    int base = h * HB;

    s8v Qf[4], Kf[4];
    #pragma unroll
    for (int t = 0; t < 4; ++t) {
        Qf[t] = *reinterpret_cast<const s8v*>(&lds[base + (t * 16 + fm) * 40 + fq * 8]);
        Kf[t] = *reinterpret_cast<const s8v*>(&lds[base + KOFF + (t * 16 + fm) * 40 + fq * 8]);
    }
    f4v S[4][4] = {};
    #pragma unroll
    for (int mt = 0; mt < 4; ++mt)
        #pragma unroll
        for (int nt = 0; nt < 4; ++nt)
            S[mt][nt] = __builtin_amdgcn_mfma_f32_16x16x32_bf16(Qf[mt], Kf[nt], S[mt][nt], 0, 0, 0);
    #pragma unroll
    for (int mt = 0; mt < 4; ++mt)
        #pragma unroll
        for (int nt = 0; nt < 4; ++nt)
            S[mt][nt] += *reinterpret_cast<const f4v*>(&btab[((h * 64 + ln) * 16 + mt * 4 + nt) * 4]);

    float rcp[16];
    #pragma unroll
    for (int mt = 0; mt < 4; ++mt) {
        #pragma unroll
        for (int r = 0; r < 4; ++r) {
            float v0 = S[mt][0][r], v1 = S[mt][1][r], v2 = S[mt][2][r], v3 = S[mt][3][r];
            if (fm != 0) v3 = -1e30f;
            float mx = fmaxf(fmaxf(v0, v1), fmaxf(v2, v3));
            #pragma unroll
            for (int off = 1; off < 16; off <<= 1) mx = fmaxf(mx, __shfl_xor(mx, off));
            float e0 = __expf(v0 - mx), e1 = __expf(v1 - mx);
            float e2 = __expf(v2 - mx), e3 = __expf(v3 - mx);
            float sm = e0 + e1 + e2 + e3;
            #pragma unroll
            for (int off = 1; off < 16; off <<= 1) sm += __shfl_xor(sm, off);
            rcp[mt * 4 + r] = 1.0f / sm;
            int row = mt * 16 + fq * 4 + r;
            ushort4 pk = { bfr(e0), bfr(e1), bfr(e2), bfr(e3) };  // k' = fm*4 + q16
            *reinterpret_cast<ushort4*>(&lds[base + row * 72 + fm * 4]) = pk;
        }
    }

    f4v O[4][2] = {};
    #pragma unroll
    for (int kt = 0; kt < 2; ++kt) {
        s8v Pf[4], Vf[2];
        #pragma unroll
        for (int mt = 0; mt < 4; ++mt)
            Pf[mt] = *reinterpret_cast<const s8v*>(&lds[base + (mt * 16 + fm) * 72 + kt * 32 + fq * 8]);
        #pragma unroll
        for (int nt = 0; nt < 2; ++nt)
            Vf[nt] = *reinterpret_cast<const s8v*>(&lds[base + VOFF + (nt * 16 + fm) * 72 + kt * 32 + fq * 8]);
        #pragma unroll
        for (int mt = 0; mt < 4; ++mt)
            #pragma unroll
            for (int nt = 0; nt < 2; ++nt)
                O[mt][nt] = __builtin_amdgcn_mfma_f32_16x16x32_bf16(Pf[mt], Vf[nt], O[mt][nt], 0, 0, 0);
    }

    size_t ob = (size_t)win * 49 * 128 + h * 32;
    #pragma unroll
    for (int mt = 0; mt < 4; ++mt)
        #pragma unroll
        for (int r = 0; r < 4; ++r) {
            int row = mt * 16 + fq * 4 + r;
            if (row < 49) {
                float sc = rcp[mt * 4 + r];
                #pragma unroll
                for (int nt = 0; nt < 2; ++nt)
                    oH[ob + (size_t)row * 128 + nt * 16 + fm] = bfr(O[mt][nt][r] * sc);
            }
        }
}

// ---------------- proj + LN2 fused: grid (gy), block owns 64 rows x 128 cols ----------------
__global__ __launch_bounds__(256) void proj_ln(
    const unsigned short* __restrict__ Ag,    // attn out bf16 [M,128]
    const unsigned short* __restrict__ W,     // outWh@0, outWl@+16384
    const float* __restrict__ bias,
    const float* __restrict__ g, const float* __restrict__ bta,
    unsigned short* __restrict__ Out, int M)
{
    __shared__ __align__(16) unsigned short As[64 * 132];
    __shared__ float red[2][2][64];
    int tid = threadIdx.x;
    int m0 = blockIdx.x * 64;
    for (int c = tid; c < 1024; c += 256) {
        int row = c >> 4, c8 = (c & 15) * 8;
        int ar = m0 + row; if (ar >= M) ar = M - 1;
        *reinterpret_cast<s8v*>(&As[row * 132 + c8]) =
            *reinterpret_cast<const s8v*>(Ag + (size_t)ar * 128 + c8);
    }
    __syncthreads();
    int wv = tid >> 6, ln = tid & 63;
    int wm = wv & 1, wn = wv >> 1;            // wn: 0..1 col halves
    int fm = ln & 15, fq = ln >> 4;
    const unsigned short* Wh = W;
    const unsigned short* Wl = W + 16384;
    f4v acc[2][4] = {};
    #pragma unroll
    for (int kk = 0; kk < 4; ++kk) {
        s8v fa[2];
        #pragma unroll
        for (int t = 0; t < 2; ++t)
            fa[t] = *reinterpret_cast<const s8v*>(&As[(wm * 32 + t * 16 + fm) * 132 + kk * 32 + fq * 8]);
        #pragma unroll
        for (int tn = 0; tn < 4; ++tn) {
            size_t wo = (size_t)(wn * 64 + tn * 16 + fm) * 128 + kk * 32 + fq * 8;
            s8v bh = *reinterpret_cast<const s8v*>(Wh + wo);
            s8v bl = *reinterpret_cast<const s8v*>(Wl + wo);
            #pragma unroll
            for (int tm = 0; tm < 2; ++tm) {
                acc[tm][tn] = __builtin_amdgcn_mfma_f32_16x16x32_bf16(fa[tm], bh, acc[tm][tn], 0, 0, 0);
                acc[tm][tn] = __builtin_amdgcn_mfma_f32_16x16x32_bf16(fa[tm], bl, acc[tm][tn], 0, 0, 0);
            }
        }
    }
    // bias + per-row sum/sumsq (16-lane shuffle, then cross-wave via LDS)
    float sumv[2][4], sqv[2][4];
    #pragma unroll
    for (int tm = 0; tm < 2; ++tm)
        #pragma unroll
        for (int r = 0; r < 4; ++r) {
            float s = 0.f, q = 0.f;
            #pragma unroll
            for (int tn = 0; tn < 4; ++tn) {
                float v = acc[tm][tn][r] + bias[wn * 64 + tn * 16 + fm];
                acc[tm][tn][r] = v;
                s += v; q += v * v;
            }
            #pragma unroll
            for (int off = 1; off < 16; off <<= 1) { s += __shfl_xor(s, off); q += __shfl_xor(q, off); }
            sumv[tm][r] = s; sqv[tm][r] = q;
        }
    if (fm == 0) {
        #pragma unroll
        for (int tm = 0; tm < 2; ++tm)
            #pragma unroll
            for (int r = 0; r < 4; ++r) {
                int row = wm * 32 + tm * 16 + fq * 4 + r;
                red[wn][0][row] = sumv[tm][r];
                red[wn][1][row] = sqv[tm][r];
            }
    }
    __syncthreads();
    #pragma unroll
    for (int tm = 0; tm < 2; ++tm)
        #pragma unroll
        for (int r = 0; r < 4; ++r) {
            int row = wm * 32 + tm * 16 + fq * 4 + r;
            int m = m0 + row;
            float s = red[0][0][row] + red[1][0][row];
            float q = red[0][1][row] + red[1][1][row];
            float mean = s * (1.0f / 128.0f);
            float var  = q * (1.0f / 128.0f) - mean * mean;
            float rstd = rsqrtf(var + 1e-5f);
            if (m < M) {
                #pragma unroll
                for (int tn = 0; tn < 4; ++tn) {
                    int n = wn * 64 + tn * 16 + fm;
                    float o = (acc[tm][tn][r] - mean) * rstd * g[n] + bta[n];
                    Out[(size_t)m * 128 + n] = bfr(o);
                }
            }
        }
}

// ---------------- fused MLP: fc1 + GELU + fc2, hidden stays in LDS ----------------
__global__ __launch_bounds__(256) void mlp_fused(
    const unsigned short* __restrict__ Ag,    // LN2 out bf16 [M,128]
    const unsigned short* __restrict__ W1,    // w1h@0, w1l@+65536
    const unsigned short* __restrict__ W2,    // w2h@0, w2l@+65536
    const float* __restrict__ b1, const float* __restrict__ b2,
    float* __restrict__ y, int M, int tbase)
{
    __shared__ __align__(16) unsigned short As[64 * 132];
    __shared__ __align__(16) unsigned short Hs[2][64 * 68];
    int tid = threadIdx.x;
    int m0 = blockIdx.x * 64;
    for (int c = tid; c < 1024; c += 256) {
        int row = c >> 4, c8 = (c & 15) * 8;
        int ar = m0 + row; if (ar >= M) ar = M - 1;
        *reinterpret_cast<s8v*>(&As[row * 132 + c8]) =
            *reinterpret_cast<const s8v*>(Ag + (size_t)ar * 128 + c8);
    }
    __syncthreads();
    int wv = tid >> 6, ln = tid & 63;
    int wm = wv & 1, wn = wv >> 1;
    int fm = ln & 15, fq = ln >> 4;
    const unsigned short* W1h = W1;
    const unsigned short* W1l = W1 + 65536;
    const unsigned short* W2h = W2;
    const unsigned short* W2l = W2 + 65536;
    f4v acc2[2][4] = {};
    for (int j = 0; j < 8; ++j) {
        int jb = j & 1;
        // fc1 chunk: hidden cols [64j, 64j+64)
        f4v acc1[2][2] = {};
        #pragma unroll
        for (int kk = 0; kk < 4; ++kk) {
            s8v fa[2], bh[2], bl[2];
            #pragma unroll
            for (int t = 0; t < 2; ++t) {
                fa[t] = *reinterpret_cast<const s8v*>(&As[(wm * 32 + t * 16 + fm) * 132 + kk * 32 + fq * 8]);
                size_t wo = (size_t)(j * 64 + wn * 32 + t * 16 + fm) * 128 + kk * 32 + fq * 8;
                bh[t] = *reinterpret_cast<const s8v*>(W1h + wo);
                bl[t] = *reinterpret_cast<const s8v*>(W1l + wo);
            }
            #pragma unroll
            for (int tm = 0; tm < 2; ++tm)
                #pragma unroll
                for (int tn = 0; tn < 2; ++tn) {
                    acc1[tm][tn] = __builtin_amdgcn_mfma_f32_16x16x32_bf16(fa[tm], bh[tn], acc1[tm][tn], 0, 0, 0);
                    acc1[tm][tn] = __builtin_amdgcn_mfma_f32_16x16x32_bf16(fa[tm], bl[tn], acc1[tm][tn], 0, 0, 0);
                }
        }
        // GELU -> bf16 -> Hs[jb]
        #pragma unroll
        for (int tm = 0; tm < 2; ++tm)
            #pragma unroll
            for (int tn = 0; tn < 2; ++tn) {
                int nl = wn * 32 + tn * 16 + fm;
                float bv = b1[j * 64 + nl];
                #pragma unroll
                for (int r = 0; r < 4; ++r) {
                    float v = acc1[tm][tn][r] + bv;
                    v = 0.5f * v * (1.0f + erff(v * 0.70710678118654752f));
                    int m = wm * 32 + tm * 16 + fq * 4 + r;
                    Hs[jb][m * 68 + nl] = bfr(v);
                }
            }
        __syncthreads();
        // fc2 partial: k in [64j, 64j+64)
        #pragma unroll
        for (int kt = 0; kt < 2; ++kt) {
            s8v hf[2], wh[4], wl[4];
            #pragma unroll
            for (int t = 0; t < 2; ++t)
                hf[t] = *reinterpret_cast<const s8v*>(&Hs[jb][(wm * 32 + t * 16 + fm) * 68 + kt * 32 + fq * 8]);
            #pragma unroll
            for (int tn = 0; tn < 4; ++tn) {
                size_t wo = (size_t)(wn * 64 + tn * 16 + fm) * 512 + j * 64 + kt * 32 + fq * 8;
                wh[tn] = *reinterpret_cast<const s8v*>(W2h + wo);
                wl[tn] = *reinterpret_cast<const s8v*>(W2l + wo);
            }
            #pragma unroll
            for (int tm = 0; tm < 2; ++tm)
                #pragma unroll
                for (int tn = 0; tn < 4; ++tn) {
                    acc2[tm][tn] = __builtin_amdgcn_mfma_f32_16x16x32_bf16(hf[tm], wh[tn], acc2[tm][tn], 0, 0, 0);
                    acc2[tm][tn] = __builtin_amdgcn_mfma_f32_16x16x32_bf16(hf[tm], wl[tn], acc2[tm][tn], 0, 0, 0);
                }
        }
    }
    // epilogue: scatter fp32 to y
    #pragma unroll
    for (int tm = 0; tm < 2; ++tm)
        #pragma unroll
        for (int tn = 0; tn < 4; ++tn) {
            int col = wn * 64 + tn * 16 + fm;
            float bv = b2[col];
            #pragma unroll
            for (int r = 0; r < 4; ++r) {
                int m = m0 + wm * 32 + tm * 16 + fq * 4 + r;
                if (m >= M) continue;
                float v = acc2[tm][tn][r] + bv;
                int t = tbase + m;
                int n = t / 49, l = t - n * 49;
                int b = n >> 6, wh_ = (n >> 3) & 7, ww = n & 7;
                int i = l / 7, jj = l - i * 7;
                size_t orow = (size_t)((b * 56 + wh_ * 7 + i) * 56 + ww * 7 + jj);
                y[orow * 128 + col] = v;
            }
        }
}

extern "C" void kernel_launch(void* const* d_in, const int* in_sizes, int n_in,
                              void* d_out, int out_size, void* d_ws, size_t ws_size,
                              hipStream_t stream) {
    const float* x    = (const float*)d_in[0];
    const float* n1g  = (const float*)d_in[1];
    const float* n1b  = (const float*)d_in[2];
    const float* qkvw = (const float*)d_in[3];
    const float* qkvb = (const float*)d_in[4];
    const float* outw = (const float*)d_in[5];
    const float* outb = (const float*)d_in[6];
    const float* pe   = (const float*)d_in[7];
    const float* n2g  = (const float*)d_in[8];
    const float* n2b  = (const float*)d_in[9];
    const float* w1   = (const float*)d_in[10];
    const float* b1   = (const float*)d_in[11];
    const float* w2   = (const float*)d_in[12];
    const float* b2   = (const float*)d_in[13];
    float* y = (float*)d_out;

    // fixed overhead: 64 KB btab + 768 KB weight planes = 851968 B
    // per-window: bufAh 12544 + bufAl 12544 + bufQK 25088 + bufV 16384 = 66560 B
    size_t wpc = NWIN;
    while (wpc > 8 && 851968 + wpc * 66560ULL > ws_size) wpc >>= 1;
    const int nchunks = (int)(NWIN / wpc);
    const size_t rows = wpc * 49;

    char* ws = (char*)d_ws;
    float* btab = (float*)ws;                                    // 64 KB
    unsigned short* wpl = (unsigned short*)(ws + 65536);         // 786432 B of planes
    unsigned short* bufAh = (unsigned short*)(ws + 851968);      // rows*128
    unsigned short* bufAl = bufAh + rows * 128;                  // rows*128
    unsigned short* bufQK = bufAl + rows * 128;                  // rows*256
    unsigned short* bufV  = bufQK + rows * 256;                  // wpc*8192
    const int gy = (int)((rows + 63) / 64);

    presplit_kernel<<<768, 256, 0, stream>>>(qkvw, outw, w1, w2, wpl);
    bias_tab_kernel<<<1, 256, 0, stream>>>(pe, btab);

    for (int c = 0; c < nchunks; ++c) {
        int tbase = (int)(c * wpc * 49);
        // LN1: fp32 gather -> hi/lo planes
        ln_kernel<<<(int)(rows / 4), 256, 0, stream>>>(x, n1g, n1b, bufAh, bufAl, tbase);
        // QKV (3-term, W direct): -> QK [rows,256] + V^T [wpc,128,64]
        qkv_gemm<<<dim3(6, gy), 256, 0, stream>>>(bufAh, bufAl, wpl, qkvb, bufQK, bufV, (int)rows);
        // attention -> bf16 [rows,128]
        attn_mfma<<<(int)wpc, 256, 0, stream>>>(bufQK, bufV, btab, bufAh);
        // proj + LN2 fused -> bf16 [rows,128]
        proj_ln<<<gy, 256, 0, stream>>>(bufAh, wpl + 98304, outb, n2g, n2b, bufAl, (int)rows);
        // fused MLP -> fp32 scatter to y
        mlp_fused<<<gy, 256, 0, stream>>>(bufAl, wpl + 131072, wpl + 262144, b1, b2, y, (int)rows, tbase);
    }
}

// Round 6
// 824.436 us; speedup vs baseline: 1.2596x; 1.2596x over previous
//
#include <hip/hip_runtime.h>
#include <hip/hip_bf16.h>

// Swin block: B=64, H=W=56, C=128, WS=7, SHIFT=3, NH=4, hd=32, hidden=512
// Round 6: revert MLP fusion (480us latency disaster: L2-latency weight loads
// serialized against barriers + erff). MLP = two LDS-staged GEMMs (proven
// structure) with single-plane RNE bf16 weights (1 MFMA/frag-pair) and 64x128
// tiles; fc2 reads hidden exactly once (grid (1,gy)). Keep round-5's LN1,
// qkv_gemm (weight-direct, zero-barrier), attn (conflict-fixed), proj_ln
// (fp32-LN fusion, absmax improved to 1.0e-3).
// ws: [0,64K) btab | [64K,64K+512K) weight planes | bufAh/Al/QK/V/H.

#define NWIN 4096
#define HB 7440    // attn per-head LDS shorts (8 banks mod 32)
#define KOFF 2568  // K section offset (4 banks mod 32)
#define VOFF 5136  // V^T section offset

typedef __attribute__((ext_vector_type(8))) short s8v;
typedef __attribute__((ext_vector_type(4))) float f4v;

__device__ __forceinline__ void split2(float v, unsigned short& h, unsigned short& l) {
    unsigned int b = __float_as_uint(v);
    h = (unsigned short)(b >> 16);                       // truncated hi
    float hf = __uint_as_float(b & 0xFFFF0000u);
    __hip_bfloat16 lo = __float2bfloat16(v - hf);        // exact residual, RNE
    l = *reinterpret_cast<unsigned short*>(&lo);
}
__device__ __forceinline__ unsigned short bfr(float v) {  // RNE bf16 bits
    __hip_bfloat16 h = __float2bfloat16(v);
    return *reinterpret_cast<unsigned short*>(&h);
}

// ---------------- weight prep (once) ----------------
// plane offsets (shorts): qkvWh 0 (49152), qkvWl 49152, outWh 98304 (16384),
//                         outWl 114688, w1r 131072 (65536, RNE), w2r 196608 (65536, RNE)
__global__ __launch_bounds__(256) void presplit_kernel(
    const float* __restrict__ qkvw, const float* __restrict__ outw,
    const float* __restrict__ w1, const float* __restrict__ w2,
    unsigned short* __restrict__ P)
{
    int i = blockIdx.x * 256 + threadIdx.x;
    if (i >= 196608) return;
    if (i < 49152) {
        float v = qkvw[i];
        if (i < 16384) v *= 0.17677669529663687f;   // fold 1/sqrt(32) into Q rows
        unsigned short h, l; split2(v, h, l);
        P[i] = h; P[49152 + i] = l;
    } else if (i < 65536) {
        int j = i - 49152; float v = outw[j];
        unsigned short h, l; split2(v, h, l);
        P[98304 + j] = h; P[114688 + j] = l;
    } else if (i < 131072) {
        int j = i - 65536;
        P[131072 + j] = bfr(w1[j]);                 // single-plane RNE
    } else {
        int j = i - 131072;
        P[196608 + j] = bfr(w2[j]);                 // single-plane RNE
    }
}

// ---------------- LN1: fp32 shift-gather in -> hi/lo planes out ----------------
__global__ __launch_bounds__(256) void ln_kernel(
    const float* __restrict__ inF,
    const float* __restrict__ g, const float* __restrict__ bta,
    unsigned short* __restrict__ outH, unsigned short* __restrict__ outL,
    int tbase)
{
    int tid = threadIdx.x;
    int wave = tid >> 6, lane = tid & 63;
    int local = blockIdx.x * 4 + wave;
    int t = tbase + local;
    int n = t / 49, l = t - n * 49;
    int b = n >> 6, wh = (n >> 3) & 7, ww = n & 7;
    int i = l / 7, j = l - i * 7;
    int hh = wh * 7 + i, wimg = ww * 7 + j;
    int sh = (hh + 53) % 56, sw = (wimg + 53) % 56;
    const float* ip = inF + (size_t)((b * 56 + sh) * 56 + sw) * 128;
    float v0 = ip[lane], v1 = ip[lane + 64];
    float s = v0 + v1, sq = v0 * v0 + v1 * v1;
    #pragma unroll
    for (int off = 32; off > 0; off >>= 1) { s += __shfl_xor(s, off); sq += __shfl_xor(sq, off); }
    float mean = s * (1.0f / 128.0f);
    float var  = sq * (1.0f / 128.0f) - mean * mean;
    float rstd = rsqrtf(var + 1e-5f);
    float r0 = (v0 - mean) * rstd * g[lane]      + bta[lane];
    float r1 = (v1 - mean) * rstd * g[lane + 64] + bta[lane + 64];
    unsigned short h0, l0, h1, l1;
    split2(r0, h0, l0); split2(r1, h1, l1);
    size_t o = (size_t)local * 128;
    outH[o + lane] = h0; outH[o + lane + 64] = h1;
    outL[o + lane] = l0; outL[o + lane + 64] = l1;
}

// ---------------- QKV GEMM: A hi/lo upfront in LDS, W direct, 3-term ----------------
__global__ __launch_bounds__(256) void qkv_gemm(
    const unsigned short* __restrict__ Agh, const unsigned short* __restrict__ Agl,
    const unsigned short* __restrict__ W,     // qkvWh@0, qkvWl@49152
    const float* __restrict__ bias,
    unsigned short* __restrict__ OutQK, unsigned short* __restrict__ OutV,
    int M)
{
    __shared__ __align__(16) unsigned short Ah[64 * 132];
    __shared__ __align__(16) unsigned short Al[64 * 132];
    int tid = threadIdx.x;
    int m0 = blockIdx.y * 64, n0 = blockIdx.x * 64;
    for (int c = tid; c < 1024; c += 256) {
        int row = c >> 4, c8 = (c & 15) * 8;
        int ar = m0 + row; if (ar >= M) ar = M - 1;
        *reinterpret_cast<s8v*>(&Ah[row * 132 + c8]) =
            *reinterpret_cast<const s8v*>(Agh + (size_t)ar * 128 + c8);
        *reinterpret_cast<s8v*>(&Al[row * 132 + c8]) =
            *reinterpret_cast<const s8v*>(Agl + (size_t)ar * 128 + c8);
    }
    __syncthreads();
    int wv = tid >> 6, ln = tid & 63;
    int wm = wv & 1, wn = wv >> 1;
    int fm = ln & 15, fq = ln >> 4;
    const unsigned short* Wh = W;
    const unsigned short* Wl = W + 49152;
    f4v acc[2][2] = {};
    #pragma unroll
    for (int kk = 0; kk < 4; ++kk) {
        s8v fah[2], fal[2], fbh[2], fbl[2];
        #pragma unroll
        for (int t = 0; t < 2; ++t) {
            int ao = (wm * 32 + t * 16 + fm) * 132 + kk * 32 + fq * 8;
            fah[t] = *reinterpret_cast<const s8v*>(&Ah[ao]);
            fal[t] = *reinterpret_cast<const s8v*>(&Al[ao]);
            size_t wo = (size_t)(n0 + wn * 32 + t * 16 + fm) * 128 + kk * 32 + fq * 8;
            fbh[t] = *reinterpret_cast<const s8v*>(Wh + wo);
            fbl[t] = *reinterpret_cast<const s8v*>(Wl + wo);
        }
        #pragma unroll
        for (int tm = 0; tm < 2; ++tm)
            #pragma unroll
            for (int tn = 0; tn < 2; ++tn) {
                acc[tm][tn] = __builtin_amdgcn_mfma_f32_16x16x32_bf16(fah[tm], fbh[tn], acc[tm][tn], 0, 0, 0);
                acc[tm][tn] = __builtin_amdgcn_mfma_f32_16x16x32_bf16(fah[tm], fbl[tn], acc[tm][tn], 0, 0, 0);
                acc[tm][tn] = __builtin_amdgcn_mfma_f32_16x16x32_bf16(fal[tm], fbh[tn], acc[tm][tn], 0, 0, 0);
            }
    }
    #pragma unroll
    for (int tm = 0; tm < 2; ++tm)
        #pragma unroll
        for (int tn = 0; tn < 2; ++tn) {
            int col = n0 + wn * 32 + tn * 16 + fm;
            float bv = bias[col];
            if (col < 128) bv *= 0.17677669529663687f;
            #pragma unroll
            for (int r = 0; r < 4; ++r) {
                int m = m0 + wm * 32 + tm * 16 + fq * 4 + r;
                if (m >= M) continue;
                float v = acc[tm][tn][r] + bv;
                if (col < 256) {
                    OutQK[(size_t)m * 256 + col] = bfr(v);
                } else {
                    int dd = col - 256, hh = dd >> 5, d = dd & 31;
                    int win = m / 49, l2 = m - win * 49;
                    int kp = (l2 & 15) * 4 + (l2 >> 4);   // k' permutation
                    OutV[((size_t)win * 128 + hh * 32 + d) * 64 + kp] = bfr(v);
                }
            }
        }
}

// ---------------- bias table in MFMA C-layout ----------------
__global__ void bias_tab_kernel(const float* __restrict__ pe, float* __restrict__ tab) {
    int t = threadIdx.x;          // 256 = 4 heads x 64 lanes
    int h = t >> 6, ln = t & 63;
    int g = ln >> 4, c = ln & 15;
    for (int mt = 0; mt < 4; ++mt)
        for (int nt = 0; nt < 4; ++nt)
            for (int r = 0; r < 4; ++r) {
                int l1 = mt * 16 + g * 4 + r, l2 = nt * 16 + c;
                float b = 0.f;
                if (l1 < 49 && l2 < 49) {
                    int i1 = l1 / 7, j1 = l1 % 7, i2 = l2 / 7, j2 = l2 % 7;
                    b = pe[h * 169 + (i1 - i2 + 6) * 13 + (j1 - j2 + 6)];
                }
                tab[((h * 64 + ln) * 16 + mt * 4 + nt) * 4 + r] = b;
            }
}

// ---------------- MFMA attention (conflict-fixed, unchanged) ----------------
__global__ __launch_bounds__(256) void attn_mfma(
    const unsigned short* __restrict__ qk,
    const unsigned short* __restrict__ vt,
    const float* __restrict__ btab,
    unsigned short* __restrict__ oH)
{
    __shared__ __align__(16) unsigned short lds[4 * HB];
    int tid = threadIdx.x;
    int win = blockIdx.x;
    const unsigned short* srcqk = qk + (size_t)win * 49 * 256;
    const unsigned short* srcv  = vt + (size_t)win * 8192;

    for (int idx = tid; idx < 1568; idx += 256) {
        int l2 = idx >> 5, c8 = idx & 31;
        int d8 = c8 * 8;
        s8v v8 = *reinterpret_cast<const s8v*>(srcqk + (size_t)l2 * 256 + d8);
        int sec = d8 >> 7, dd = d8 & 127, hh = dd >> 5, kk = dd & 31;
        *reinterpret_cast<s8v*>(&lds[hh * HB + (sec ? KOFF : 0) + l2 * 40 + kk]) = v8;
    }
    for (int idx = tid; idx < 1024; idx += 256) {
        int row = idx >> 3, j = idx & 7;
        s8v v8 = *reinterpret_cast<const s8v*>(srcv + (size_t)row * 64 + j * 8);
        int hh = row >> 5, d = row & 31;
        *reinterpret_cast<s8v*>(&lds[hh * HB + VOFF + d * 72 + j * 8]) = v8;
    }
    __syncthreads();
    for (int i = tid; i < 1920; i += 256) {
        int hh = i / 480, rem = i % 480, d = rem / 15, j = rem % 15;
        lds[hh * HB + VOFF + d * 72 + (j + 1) * 4 + 3] = 0;
    }
    __syncthreads();

    int h = tid >> 6, ln = tid & 63;
    int fm = ln & 15, fq = ln >> 4;
    int base = h * HB;

    s8v Qf[4], Kf[4];
    #pragma unroll
    for (int t = 0; t < 4; ++t) {
        Qf[t] = *reinterpret_cast<const s8v*>(&lds[base + (t * 16 + fm) * 40 + fq * 8]);
        Kf[t] = *reinterpret_cast<const s8v*>(&lds[base + KOFF + (t * 16 + fm) * 40 + fq * 8]);
    }
    f4v S[4][4] = {};
    #pragma unroll
    for (int mt = 0; mt < 4; ++mt)
        #pragma unroll
        for (int nt = 0; nt < 4; ++nt)
            S[mt][nt] = __builtin_amdgcn_mfma_f32_16x16x32_bf16(Qf[mt], Kf[nt], S[mt][nt], 0, 0, 0);
    #pragma unroll
    for (int mt = 0; mt < 4; ++mt)
        #pragma unroll
        for (int nt = 0; nt < 4; ++nt)
            S[mt][nt] += *reinterpret_cast<const f4v*>(&btab[((h * 64 + ln) * 16 + mt * 4 + nt) * 4]);

    float rcp[16];
    #pragma unroll
    for (int mt = 0; mt < 4; ++mt) {
        #pragma unroll
        for (int r = 0; r < 4; ++r) {
            float v0 = S[mt][0][r], v1 = S[mt][1][r], v2 = S[mt][2][r], v3 = S[mt][3][r];
            if (fm != 0) v3 = -1e30f;
            float mx = fmaxf(fmaxf(v0, v1), fmaxf(v2, v3));
            #pragma unroll
            for (int off = 1; off < 16; off <<= 1) mx = fmaxf(mx, __shfl_xor(mx, off));
            float e0 = __expf(v0 - mx), e1 = __expf(v1 - mx);
            float e2 = __expf(v2 - mx), e3 = __expf(v3 - mx);
            float sm = e0 + e1 + e2 + e3;
            #pragma unroll
            for (int off = 1; off < 16; off <<= 1) sm += __shfl_xor(sm, off);
            rcp[mt * 4 + r] = 1.0f / sm;
            int row = mt * 16 + fq * 4 + r;
            ushort4 pk = { bfr(e0), bfr(e1), bfr(e2), bfr(e3) };  // k' = fm*4 + q16
            *reinterpret_cast<ushort4*>(&lds[base + row * 72 + fm * 4]) = pk;
        }
    }

    f4v O[4][2] = {};
    #pragma unroll
    for (int kt = 0; kt < 2; ++kt) {
        s8v Pf[4], Vf[2];
        #pragma unroll
        for (int mt = 0; mt < 4; ++mt)
            Pf[mt] = *reinterpret_cast<const s8v*>(&lds[base + (mt * 16 + fm) * 72 + kt * 32 + fq * 8]);
        #pragma unroll
        for (int nt = 0; nt < 2; ++nt)
            Vf[nt] = *reinterpret_cast<const s8v*>(&lds[base + VOFF + (nt * 16 + fm) * 72 + kt * 32 + fq * 8]);
        #pragma unroll
        for (int mt = 0; mt < 4; ++mt)
            #pragma unroll
            for (int nt = 0; nt < 2; ++nt)
                O[mt][nt] = __builtin_amdgcn_mfma_f32_16x16x32_bf16(Pf[mt], Vf[nt], O[mt][nt], 0, 0, 0);
    }

    size_t ob = (size_t)win * 49 * 128 + h * 32;
    #pragma unroll
    for (int mt = 0; mt < 4; ++mt)
        #pragma unroll
        for (int r = 0; r < 4; ++r) {
            int row = mt * 16 + fq * 4 + r;
            if (row < 49) {
                float sc = rcp[mt * 4 + r];
                #pragma unroll
                for (int nt = 0; nt < 2; ++nt)
                    oH[ob + (size_t)row * 128 + nt * 16 + fm] = bfr(O[mt][nt][r] * sc);
            }
        }
}

// ---------------- proj + LN2 fused (unchanged) ----------------
__global__ __launch_bounds__(256) void proj_ln(
    const unsigned short* __restrict__ Ag,    // attn out bf16 [M,128]
    const unsigned short* __restrict__ W,     // outWh@0, outWl@+16384
    const float* __restrict__ bias,
    const float* __restrict__ g, const float* __restrict__ bta,
    unsigned short* __restrict__ Out, int M)
{
    __shared__ __align__(16) unsigned short As[64 * 132];
    __shared__ float red[2][2][64];
    int tid = threadIdx.x;
    int m0 = blockIdx.x * 64;
    for (int c = tid; c < 1024; c += 256) {
        int row = c >> 4, c8 = (c & 15) * 8;
        int ar = m0 + row; if (ar >= M) ar = M - 1;
        *reinterpret_cast<s8v*>(&As[row * 132 + c8]) =
            *reinterpret_cast<const s8v*>(Ag + (size_t)ar * 128 + c8);
    }
    __syncthreads();
    int wv = tid >> 6, ln = tid & 63;
    int wm = wv & 1, wn = wv >> 1;
    int fm = ln & 15, fq = ln >> 4;
    const unsigned short* Wh = W;
    const unsigned short* Wl = W + 16384;
    f4v acc[2][4] = {};
    #pragma unroll
    for (int kk = 0; kk < 4; ++kk) {
        s8v fa[2];
        #pragma unroll
        for (int t = 0; t < 2; ++t)
            fa[t] = *reinterpret_cast<const s8v*>(&As[(wm * 32 + t * 16 + fm) * 132 + kk * 32 + fq * 8]);
        #pragma unroll
        for (int tn = 0; tn < 4; ++tn) {
            size_t wo = (size_t)(wn * 64 + tn * 16 + fm) * 128 + kk * 32 + fq * 8;
            s8v bh = *reinterpret_cast<const s8v*>(Wh + wo);
            s8v bl = *reinterpret_cast<const s8v*>(Wl + wo);
            #pragma unroll
            for (int tm = 0; tm < 2; ++tm) {
                acc[tm][tn] = __builtin_amdgcn_mfma_f32_16x16x32_bf16(fa[tm], bh, acc[tm][tn], 0, 0, 0);
                acc[tm][tn] = __builtin_amdgcn_mfma_f32_16x16x32_bf16(fa[tm], bl, acc[tm][tn], 0, 0, 0);
            }
        }
    }
    float sumv[2][4], sqv[2][4];
    #pragma unroll
    for (int tm = 0; tm < 2; ++tm)
        #pragma unroll
        for (int r = 0; r < 4; ++r) {
            float s = 0.f, q = 0.f;
            #pragma unroll
            for (int tn = 0; tn < 4; ++tn) {
                float v = acc[tm][tn][r] + bias[wn * 64 + tn * 16 + fm];
                acc[tm][tn][r] = v;
                s += v; q += v * v;
            }
            #pragma unroll
            for (int off = 1; off < 16; off <<= 1) { s += __shfl_xor(s, off); q += __shfl_xor(q, off); }
            sumv[tm][r] = s; sqv[tm][r] = q;
        }
    if (fm == 0) {
        #pragma unroll
        for (int tm = 0; tm < 2; ++tm)
            #pragma unroll
            for (int r = 0; r < 4; ++r) {
                int row = wm * 32 + tm * 16 + fq * 4 + r;
                red[wn][0][row] = sumv[tm][r];
                red[wn][1][row] = sqv[tm][r];
            }
    }
    __syncthreads();
    #pragma unroll
    for (int tm = 0; tm < 2; ++tm)
        #pragma unroll
        for (int r = 0; r < 4; ++r) {
            int row = wm * 32 + tm * 16 + fq * 4 + r;
            int m = m0 + row;
            float s = red[0][0][row] + red[1][0][row];
            float q = red[0][1][row] + red[1][1][row];
            float mean = s * (1.0f / 128.0f);
            float var  = q * (1.0f / 128.0f) - mean * mean;
            float rstd = rsqrtf(var + 1e-5f);
            if (m < M) {
                #pragma unroll
                for (int tn = 0; tn < 4; ++tn) {
                    int n = wn * 64 + tn * 16 + fm;
                    float o = (acc[tm][tn][r] - mean) * rstd * g[n] + bta[n];
                    Out[(size_t)m * 128 + n] = bfr(o);
                }
            }
        }
}

// ---------------- MLP GEMM: 64x128 tile, LDS-staged A and W, single-plane bf16 ----------------
// mode 1: GELU + bf16 out [M,N]; mode 3: fp32 scatter-remap out (fc2 -> y, N=128)
__global__ __launch_bounds__(256) void gemm_w(
    const unsigned short* __restrict__ A, const unsigned short* __restrict__ W,
    const float* __restrict__ bias,
    float* __restrict__ OutF, unsigned short* __restrict__ OutH,
    int M, int N, int K, int mode, int tbase)
{
    __shared__ __align__(16) unsigned short As[64 * 40];
    __shared__ __align__(16) unsigned short Ws[128 * 40];
    int tid = threadIdx.x;
    int wv = tid >> 6, ln = tid & 63;
    int wm = wv & 1, wn = wv >> 1;
    int fm = ln & 15, fq = ln >> 4;
    int m0 = blockIdx.y * 64, n0 = blockIdx.x * 128;
    int sr = tid >> 2, sk = (tid & 3) * 8;
    int arow = m0 + sr; if (arow >= M) arow = M - 1;
    const unsigned short* pA  = A + (size_t)arow * K + sk;
    const unsigned short* pW0 = W + (size_t)(n0 + sr) * K + sk;
    const unsigned short* pW1 = W + (size_t)(n0 + 64 + sr) * K + sk;
    int so = sr * 40 + sk;

    f4v acc[2][4] = {};
    s8v ra, rw0, rw1;
    #define LOADK(k0) do { \
        ra  = *reinterpret_cast<const s8v*>(pA  + (k0)); \
        rw0 = *reinterpret_cast<const s8v*>(pW0 + (k0)); \
        rw1 = *reinterpret_cast<const s8v*>(pW1 + (k0)); } while (0)
    LOADK(0);
    for (int k0 = 0; k0 < K; k0 += 32) {
        *reinterpret_cast<s8v*>(&As[so]) = ra;
        *reinterpret_cast<s8v*>(&Ws[so]) = rw0;
        *reinterpret_cast<s8v*>(&Ws[2560 + so]) = rw1;
        __syncthreads();
        if (k0 + 32 < K) LOADK(k0 + 32);        // prefetch next k-step
        s8v fa[2], fb[4];
        #pragma unroll
        for (int t = 0; t < 2; ++t)
            fa[t] = *reinterpret_cast<const s8v*>(&As[(wm * 32 + t * 16 + fm) * 40 + fq * 8]);
        #pragma unroll
        for (int t = 0; t < 4; ++t)
            fb[t] = *reinterpret_cast<const s8v*>(&Ws[(wn * 64 + t * 16 + fm) * 40 + fq * 8]);
        #pragma unroll
        for (int tm = 0; tm < 2; ++tm)
            #pragma unroll
            for (int tn = 0; tn < 4; ++tn)
                acc[tm][tn] = __builtin_amdgcn_mfma_f32_16x16x32_bf16(fa[tm], fb[tn], acc[tm][tn], 0, 0, 0);
        __syncthreads();
    }
    #undef LOADK

    #pragma unroll
    for (int tm = 0; tm < 2; ++tm)
        #pragma unroll
        for (int tn = 0; tn < 4; ++tn) {
            int col = n0 + wn * 64 + tn * 16 + fm;
            float bv = bias[col];
            #pragma unroll
            for (int r = 0; r < 4; ++r) {
                int m = m0 + wm * 32 + tm * 16 + fq * 4 + r;
                if (m >= M) continue;
                float v = acc[tm][tn][r] + bv;
                if (mode == 1) {
                    v = 0.5f * v * (1.0f + erff(v * 0.70710678118654752f));
                    OutH[(size_t)m * N + col] = bfr(v);
                } else {
                    int t = tbase + m;
                    int n = t / 49, l = t - n * 49;
                    int b = n >> 6, wh_ = (n >> 3) & 7, ww = n & 7;
                    int i = l / 7, jj = l - i * 7;
                    size_t orow = (size_t)((b * 56 + wh_ * 7 + i) * 56 + ww * 7 + jj);
                    OutF[orow * N + col] = v;
                }
            }
        }
}

extern "C" void kernel_launch(void* const* d_in, const int* in_sizes, int n_in,
                              void* d_out, int out_size, void* d_ws, size_t ws_size,
                              hipStream_t stream) {
    const float* x    = (const float*)d_in[0];
    const float* n1g  = (const float*)d_in[1];
    const float* n1b  = (const float*)d_in[2];
    const float* qkvw = (const float*)d_in[3];
    const float* qkvb = (const float*)d_in[4];
    const float* outw = (const float*)d_in[5];
    const float* outb = (const float*)d_in[6];
    const float* pe   = (const float*)d_in[7];
    const float* n2g  = (const float*)d_in[8];
    const float* n2b  = (const float*)d_in[9];
    const float* w1   = (const float*)d_in[10];
    const float* b1   = (const float*)d_in[11];
    const float* w2   = (const float*)d_in[12];
    const float* b2   = (const float*)d_in[13];
    float* y = (float*)d_out;

    // fixed overhead: 64 KB btab + 512 KB weight planes = 589824 B
    // per-window: bufAh 12544 + bufAl 12544 + bufQK 25088 + bufV 16384 + bufH 50176 = 116736 B
    size_t wpc = NWIN;
    while (wpc > 8 && 589824 + wpc * 116736ULL > ws_size) wpc >>= 1;
    const int nchunks = (int)(NWIN / wpc);
    const size_t rows = wpc * 49;

    char* ws = (char*)d_ws;
    float* btab = (float*)ws;                                    // 64 KB
    unsigned short* wpl = (unsigned short*)(ws + 65536);         // 524288 B of planes
    unsigned short* bufAh = (unsigned short*)(ws + 589824);      // rows*128
    unsigned short* bufAl = bufAh + rows * 128;                  // rows*128
    unsigned short* bufQK = bufAl + rows * 128;                  // rows*256
    unsigned short* bufV  = bufQK + rows * 256;                  // wpc*8192
    unsigned short* bufH  = bufV + wpc * 8192;                   // rows*512
    const int gy = (int)((rows + 63) / 64);

    presplit_kernel<<<768, 256, 0, stream>>>(qkvw, outw, w1, w2, wpl);
    bias_tab_kernel<<<1, 256, 0, stream>>>(pe, btab);

    for (int c = 0; c < nchunks; ++c) {
        int tbase = (int)(c * wpc * 49);
        // LN1: fp32 gather -> hi/lo planes
        ln_kernel<<<(int)(rows / 4), 256, 0, stream>>>(x, n1g, n1b, bufAh, bufAl, tbase);
        // QKV (3-term, W direct): -> QK [rows,256] + V^T [wpc,128,64]
        qkv_gemm<<<dim3(6, gy), 256, 0, stream>>>(bufAh, bufAl, wpl, qkvb, bufQK, bufV, (int)rows);
        // attention -> bf16 [rows,128]
        attn_mfma<<<(int)wpc, 256, 0, stream>>>(bufQK, bufV, btab, bufAh);
        // proj + LN2 fused -> bf16 [rows,128]
        proj_ln<<<gy, 256, 0, stream>>>(bufAh, wpl + 98304, outb, n2g, n2b, bufAl, (int)rows);
        // fc1 + GELU: 64x128 tiles, single-plane W -> bf16 hidden [rows,512]
        gemm_w<<<dim3(4, gy), 256, 0, stream>>>(
            bufAl, wpl + 131072, b1, nullptr, bufH, (int)rows, 512, 128, 1, 0);
        // fc2: hidden read once (grid x=1) -> fp32 scatter to y
        gemm_w<<<dim3(1, gy), 256, 0, stream>>>(
            bufH, wpl + 196608, b2, y, nullptr, (int)rows, 128, 512, 3, tbase);
    }
}

// Round 7
// 709.309 us; speedup vs baseline: 1.4641x; 1.1623x over previous
//
#include <hip/hip_runtime.h>
#include <hip/hip_bf16.h>

// Swin block: B=64, H=W=56, C=128, WS=7, SHIFT=3, NH=4, hd=32, hidden=512
// Round 7: (a) LN1 fused into QKV GEMM staging (kills LN1 kernel + its 206MB
// round-trip; x is L3-resident across the 6 col-blocks); (b) proj_ln now
// LDS-stages its weight per k-step (R6 proved weight-direct = latency-bound:
// qkv 95->134us) and uses single-plane RNE W (error flows only through LN2;
// no residual path); (c) attn / fc1 / fc2 unchanged from R6 (proven).
// All GEMM k-loops: LDS-staged operands, 2-barrier, register prefetch.
// ws: [0,64K) btab | 480K weight planes | bufQK | bufV | bufO | bufL | bufH.

#define NWIN 4096
#define HB 7440    // attn per-head LDS shorts (8 banks mod 32)
#define KOFF 2568  // K section offset (4 banks mod 32)
#define VOFF 5136  // V^T section offset

typedef __attribute__((ext_vector_type(8))) short s8v;
typedef __attribute__((ext_vector_type(4))) float f4v;

__device__ __forceinline__ void split2(float v, unsigned short& h, unsigned short& l) {
    unsigned int b = __float_as_uint(v);
    h = (unsigned short)(b >> 16);                       // truncated hi
    float hf = __uint_as_float(b & 0xFFFF0000u);
    __hip_bfloat16 lo = __float2bfloat16(v - hf);        // exact residual, RNE
    l = *reinterpret_cast<unsigned short*>(&lo);
}
__device__ __forceinline__ unsigned short bfr(float v) {  // RNE bf16 bits
    __hip_bfloat16 h = __float2bfloat16(v);
    return *reinterpret_cast<unsigned short*>(&h);
}

// ---------------- weight prep (once) ----------------
// plane offsets (shorts): qkvWh 0 (49152), qkvWl 49152, outWr 98304 (16384, RNE),
//                         w1r 114688 (65536, RNE), w2r 180224 (65536, RNE)
__global__ __launch_bounds__(256) void presplit_kernel(
    const float* __restrict__ qkvw, const float* __restrict__ outw,
    const float* __restrict__ w1, const float* __restrict__ w2,
    unsigned short* __restrict__ P)
{
    int i = blockIdx.x * 256 + threadIdx.x;
    if (i >= 196608) return;
    if (i < 49152) {
        float v = qkvw[i];
        if (i < 16384) v *= 0.17677669529663687f;   // fold 1/sqrt(32) into Q rows
        unsigned short h, l; split2(v, h, l);
        P[i] = h; P[49152 + i] = l;
    } else if (i < 65536) {
        int j = i - 49152;
        P[98304 + j] = bfr(outw[j]);                // single-plane RNE
    } else if (i < 131072) {
        int j = i - 65536;
        P[114688 + j] = bfr(w1[j]);
    } else {
        int j = i - 131072;
        P[180224 + j] = bfr(w2[j]);
    }
}

// ---------------- fused LN1 + QKV GEMM ----------------
// 64x64 tile, grid (6, gy). Staging threads (4/row) gather shifted x rows,
// compute LN in registers (4-lane shuffle reduce), split2 -> A hi/lo regs;
// k-loop stages A regs + prefetched W hi/lo per step (2-barrier). 3-term MFMA.
// Epilogue: QK coalesced [M,256] (Q pre-scaled), V k'-scatter [win,128,64].
__global__ __launch_bounds__(256) void ln_qkv(
    const float* __restrict__ x,
    const float* __restrict__ g, const float* __restrict__ bta,
    const unsigned short* __restrict__ W,     // qkvWh@0, qkvWl@49152
    const float* __restrict__ bias,
    unsigned short* __restrict__ OutQK, unsigned short* __restrict__ OutV,
    int M, int tbase)
{
    __shared__ __align__(16) unsigned short Ah[64 * 40];
    __shared__ __align__(16) unsigned short Al[64 * 40];
    __shared__ __align__(16) unsigned short Wh[64 * 40];
    __shared__ __align__(16) unsigned short Wl[64 * 40];
    int tid = threadIdx.x;
    int m0 = blockIdx.y * 64, n0 = blockIdx.x * 64;
    int sr = tid >> 2, sq = (tid & 3) * 8;
    int ar = m0 + sr; if (ar >= M) ar = M - 1;
    // shifted-window gather for token tbase+ar
    int t = tbase + ar;
    int n = t / 49, l = t - n * 49;
    int b = n >> 6, wh_ = (n >> 3) & 7, ww = n & 7;
    int i = l / 7, j = l - i * 7;
    int sh = (wh_ * 7 + i + 53) % 56, sw = (ww * 7 + j + 53) % 56;
    const float* ip = x + (size_t)((b * 56 + sh) * 56 + sw) * 128;

    // load 32 cols (this thread's share), LN stats via 4-lane reduce
    float v[4][8];
    float s = 0.f, q2 = 0.f;
    #pragma unroll
    for (int kc = 0; kc < 4; ++kc) {
        float4 a = *reinterpret_cast<const float4*>(ip + kc * 32 + sq);
        float4 c = *reinterpret_cast<const float4*>(ip + kc * 32 + sq + 4);
        v[kc][0] = a.x; v[kc][1] = a.y; v[kc][2] = a.z; v[kc][3] = a.w;
        v[kc][4] = c.x; v[kc][5] = c.y; v[kc][6] = c.z; v[kc][7] = c.w;
        #pragma unroll
        for (int e = 0; e < 8; ++e) { s += v[kc][e]; q2 += v[kc][e] * v[kc][e]; }
    }
    s  += __shfl_xor(s, 1);  s  += __shfl_xor(s, 2);
    q2 += __shfl_xor(q2, 1); q2 += __shfl_xor(q2, 2);
    float mean = s * (1.0f / 128.0f);
    float var  = q2 * (1.0f / 128.0f) - mean * mean;
    float rstd = rsqrtf(var + 1e-5f);
    unsigned short ah[4][8], al[4][8];
    #pragma unroll
    for (int kc = 0; kc < 4; ++kc)
        #pragma unroll
        for (int e = 0; e < 8; ++e) {
            int c = kc * 32 + sq + e;
            float r = (v[kc][e] - mean) * rstd * g[c] + bta[c];
            split2(r, ah[kc][e], al[kc][e]);
        }

    int wv = tid >> 6, ln = tid & 63;
    int wm = wv & 1, wn = wv >> 1;
    int fm = ln & 15, fq = ln >> 4;
    const unsigned short* Whg = W;
    const unsigned short* Wlg = W + 49152;
    size_t wrow = (size_t)(n0 + sr) * 128 + sq;
    int so = sr * 40 + sq;
    s8v rwh = *reinterpret_cast<const s8v*>(Whg + wrow);
    s8v rwl = *reinterpret_cast<const s8v*>(Wlg + wrow);

    f4v acc[2][2] = {};
    #pragma unroll
    for (int kc = 0; kc < 4; ++kc) {
        *reinterpret_cast<s8v*>(&Ah[so]) = *reinterpret_cast<const s8v*>(ah[kc]);
        *reinterpret_cast<s8v*>(&Al[so]) = *reinterpret_cast<const s8v*>(al[kc]);
        *reinterpret_cast<s8v*>(&Wh[so]) = rwh;
        *reinterpret_cast<s8v*>(&Wl[so]) = rwl;
        __syncthreads();
        if (kc < 3) {
            rwh = *reinterpret_cast<const s8v*>(Whg + wrow + (kc + 1) * 32);
            rwl = *reinterpret_cast<const s8v*>(Wlg + wrow + (kc + 1) * 32);
        }
        s8v fah[2], fal[2], fbh[2], fbl[2];
        #pragma unroll
        for (int tt = 0; tt < 2; ++tt) {
            int ao = (wm * 32 + tt * 16 + fm) * 40 + fq * 8;
            fah[tt] = *reinterpret_cast<const s8v*>(&Ah[ao]);
            fal[tt] = *reinterpret_cast<const s8v*>(&Al[ao]);
            int bo = (wn * 32 + tt * 16 + fm) * 40 + fq * 8;
            fbh[tt] = *reinterpret_cast<const s8v*>(&Wh[bo]);
            fbl[tt] = *reinterpret_cast<const s8v*>(&Wl[bo]);
        }
        #pragma unroll
        for (int tm = 0; tm < 2; ++tm)
            #pragma unroll
            for (int tn = 0; tn < 2; ++tn) {
                acc[tm][tn] = __builtin_amdgcn_mfma_f32_16x16x32_bf16(fah[tm], fbh[tn], acc[tm][tn], 0, 0, 0);
                acc[tm][tn] = __builtin_amdgcn_mfma_f32_16x16x32_bf16(fah[tm], fbl[tn], acc[tm][tn], 0, 0, 0);
                acc[tm][tn] = __builtin_amdgcn_mfma_f32_16x16x32_bf16(fal[tm], fbh[tn], acc[tm][tn], 0, 0, 0);
            }
        __syncthreads();
    }

    #pragma unroll
    for (int tm = 0; tm < 2; ++tm)
        #pragma unroll
        for (int tn = 0; tn < 2; ++tn) {
            int col = n0 + wn * 32 + tn * 16 + fm;
            float bv = bias[col];
            if (col < 128) bv *= 0.17677669529663687f;
            #pragma unroll
            for (int r = 0; r < 4; ++r) {
                int m = m0 + wm * 32 + tm * 16 + fq * 4 + r;
                if (m >= M) continue;
                float vv = acc[tm][tn][r] + bv;
                if (col < 256) {
                    OutQK[(size_t)m * 256 + col] = bfr(vv);
                } else {
                    int dd = col - 256, hh = dd >> 5, d = dd & 31;
                    int win = m / 49, l2 = m - win * 49;
                    int kp = (l2 & 15) * 4 + (l2 >> 4);   // k' permutation
                    OutV[((size_t)win * 128 + hh * 32 + d) * 64 + kp] = bfr(vv);
                }
            }
        }
}

// ---------------- bias table in MFMA C-layout ----------------
__global__ void bias_tab_kernel(const float* __restrict__ pe, float* __restrict__ tab) {
    int t = threadIdx.x;          // 256 = 4 heads x 64 lanes
    int h = t >> 6, ln = t & 63;
    int g = ln >> 4, c = ln & 15;
    for (int mt = 0; mt < 4; ++mt)
        for (int nt = 0; nt < 4; ++nt)
            for (int r = 0; r < 4; ++r) {
                int l1 = mt * 16 + g * 4 + r, l2 = nt * 16 + c;
                float b = 0.f;
                if (l1 < 49 && l2 < 49) {
                    int i1 = l1 / 7, j1 = l1 % 7, i2 = l2 / 7, j2 = l2 % 7;
                    b = pe[h * 169 + (i1 - i2 + 6) * 13 + (j1 - j2 + 6)];
                }
                tab[((h * 64 + ln) * 16 + mt * 4 + nt) * 4 + r] = b;
            }
}

// ---------------- MFMA attention (conflict-fixed, unchanged from R6) ----------------
__global__ __launch_bounds__(256) void attn_mfma(
    const unsigned short* __restrict__ qk,
    const unsigned short* __restrict__ vt,
    const float* __restrict__ btab,
    unsigned short* __restrict__ oH)
{
    __shared__ __align__(16) unsigned short lds[4 * HB];
    int tid = threadIdx.x;
    int win = blockIdx.x;
    const unsigned short* srcqk = qk + (size_t)win * 49 * 256;
    const unsigned short* srcv  = vt + (size_t)win * 8192;

    for (int idx = tid; idx < 1568; idx += 256) {
        int l2 = idx >> 5, c8 = idx & 31;
        int d8 = c8 * 8;
        s8v v8 = *reinterpret_cast<const s8v*>(srcqk + (size_t)l2 * 256 + d8);
        int sec = d8 >> 7, dd = d8 & 127, hh = dd >> 5, kk = dd & 31;
        *reinterpret_cast<s8v*>(&lds[hh * HB + (sec ? KOFF : 0) + l2 * 40 + kk]) = v8;
    }
    for (int idx = tid; idx < 1024; idx += 256) {
        int row = idx >> 3, j = idx & 7;
        s8v v8 = *reinterpret_cast<const s8v*>(srcv + (size_t)row * 64 + j * 8);
        int hh = row >> 5, d = row & 31;
        *reinterpret_cast<s8v*>(&lds[hh * HB + VOFF + d * 72 + j * 8]) = v8;
    }
    __syncthreads();
    for (int i = tid; i < 1920; i += 256) {
        int hh = i / 480, rem = i % 480, d = rem / 15, j = rem % 15;
        lds[hh * HB + VOFF + d * 72 + (j + 1) * 4 + 3] = 0;
    }
    __syncthreads();

    int h = tid >> 6, ln = tid & 63;
    int fm = ln & 15, fq = ln >> 4;
    int base = h * HB;

    s8v Qf[4], Kf[4];
    #pragma unroll
    for (int t = 0; t < 4; ++t) {
        Qf[t] = *reinterpret_cast<const s8v*>(&lds[base + (t * 16 + fm) * 40 + fq * 8]);
        Kf[t] = *reinterpret_cast<const s8v*>(&lds[base + KOFF + (t * 16 + fm) * 40 + fq * 8]);
    }
    f4v S[4][4] = {};
    #pragma unroll
    for (int mt = 0; mt < 4; ++mt)
        #pragma unroll
        for (int nt = 0; nt < 4; ++nt)
            S[mt][nt] = __builtin_amdgcn_mfma_f32_16x16x32_bf16(Qf[mt], Kf[nt], S[mt][nt], 0, 0, 0);
    #pragma unroll
    for (int mt = 0; mt < 4; ++mt)
        #pragma unroll
        for (int nt = 0; nt < 4; ++nt)
            S[mt][nt] += *reinterpret_cast<const f4v*>(&btab[((h * 64 + ln) * 16 + mt * 4 + nt) * 4]);

    float rcp[16];
    #pragma unroll
    for (int mt = 0; mt < 4; ++mt) {
        #pragma unroll
        for (int r = 0; r < 4; ++r) {
            float v0 = S[mt][0][r], v1 = S[mt][1][r], v2 = S[mt][2][r], v3 = S[mt][3][r];
            if (fm != 0) v3 = -1e30f;
            float mx = fmaxf(fmaxf(v0, v1), fmaxf(v2, v3));
            #pragma unroll
            for (int off = 1; off < 16; off <<= 1) mx = fmaxf(mx, __shfl_xor(mx, off));
            float e0 = __expf(v0 - mx), e1 = __expf(v1 - mx);
            float e2 = __expf(v2 - mx), e3 = __expf(v3 - mx);
            float sm = e0 + e1 + e2 + e3;
            #pragma unroll
            for (int off = 1; off < 16; off <<= 1) sm += __shfl_xor(sm, off);
            rcp[mt * 4 + r] = 1.0f / sm;
            int row = mt * 16 + fq * 4 + r;
            ushort4 pk = { bfr(e0), bfr(e1), bfr(e2), bfr(e3) };  // k' = fm*4 + q16
            *reinterpret_cast<ushort4*>(&lds[base + row * 72 + fm * 4]) = pk;
        }
    }

    f4v O[4][2] = {};
    #pragma unroll
    for (int kt = 0; kt < 2; ++kt) {
        s8v Pf[4], Vf[2];
        #pragma unroll
        for (int mt = 0; mt < 4; ++mt)
            Pf[mt] = *reinterpret_cast<const s8v*>(&lds[base + (mt * 16 + fm) * 72 + kt * 32 + fq * 8]);
        #pragma unroll
        for (int nt = 0; nt < 2; ++nt)
            Vf[nt] = *reinterpret_cast<const s8v*>(&lds[base + VOFF + (nt * 16 + fm) * 72 + kt * 32 + fq * 8]);
        #pragma unroll
        for (int mt = 0; mt < 4; ++mt)
            #pragma unroll
            for (int nt = 0; nt < 2; ++nt)
                O[mt][nt] = __builtin_amdgcn_mfma_f32_16x16x32_bf16(Pf[mt], Vf[nt], O[mt][nt], 0, 0, 0);
    }

    size_t ob = (size_t)win * 49 * 128 + h * 32;
    #pragma unroll
    for (int mt = 0; mt < 4; ++mt)
        #pragma unroll
        for (int r = 0; r < 4; ++r) {
            int row = mt * 16 + fq * 4 + r;
            if (row < 49) {
                float sc = rcp[mt * 4 + r];
                #pragma unroll
                for (int nt = 0; nt < 2; ++nt)
                    oH[ob + (size_t)row * 128 + nt * 16 + fm] = bfr(O[mt][nt][r] * sc);
            }
        }
}

// ---------------- proj + LN2 fused: LDS-staged single-plane W ----------------
__global__ __launch_bounds__(256) void proj_ln(
    const unsigned short* __restrict__ Ag,    // attn out bf16 [M,128]
    const unsigned short* __restrict__ Wg,    // outWr [128,128] RNE bf16
    const float* __restrict__ bias,
    const float* __restrict__ g, const float* __restrict__ bta,
    unsigned short* __restrict__ Out, int M)
{
    __shared__ __align__(16) unsigned short As[64 * 132];
    __shared__ __align__(16) unsigned short Ws[128 * 40];
    __shared__ float red[2][2][64];
    int tid = threadIdx.x;
    int m0 = blockIdx.x * 64;
    for (int c = tid; c < 1024; c += 256) {
        int row = c >> 4, c8 = (c & 15) * 8;
        int ar = m0 + row; if (ar >= M) ar = M - 1;
        *reinterpret_cast<s8v*>(&As[row * 132 + c8]) =
            *reinterpret_cast<const s8v*>(Ag + (size_t)ar * 128 + c8);
    }
    int w0r = tid >> 2, w0c = (tid & 3) * 8;      // rows 0..63
    int w1r = 64 + w0r;                           // rows 64..127
    s8v rw0 = *reinterpret_cast<const s8v*>(Wg + (size_t)w0r * 128 + w0c);
    s8v rw1 = *reinterpret_cast<const s8v*>(Wg + (size_t)w1r * 128 + w0c);

    int wv = tid >> 6, ln = tid & 63;
    int wm = wv & 1, wn = wv >> 1;
    int fm = ln & 15, fq = ln >> 4;
    f4v acc[2][4] = {};
    for (int kc = 0; kc < 4; ++kc) {
        *reinterpret_cast<s8v*>(&Ws[w0r * 40 + w0c]) = rw0;
        *reinterpret_cast<s8v*>(&Ws[w1r * 40 + w0c]) = rw1;
        __syncthreads();                           // covers As (kc=0) + Ws
        if (kc < 3) {
            rw0 = *reinterpret_cast<const s8v*>(Wg + (size_t)w0r * 128 + (kc + 1) * 32 + w0c);
            rw1 = *reinterpret_cast<const s8v*>(Wg + (size_t)w1r * 128 + (kc + 1) * 32 + w0c);
        }
        s8v fa[2], fb[4];
        #pragma unroll
        for (int t = 0; t < 2; ++t)
            fa[t] = *reinterpret_cast<const s8v*>(&As[(wm * 32 + t * 16 + fm) * 132 + kc * 32 + fq * 8]);
        #pragma unroll
        for (int t = 0; t < 4; ++t)
            fb[t] = *reinterpret_cast<const s8v*>(&Ws[(wn * 64 + t * 16 + fm) * 40 + fq * 8]);
        #pragma unroll
        for (int tm = 0; tm < 2; ++tm)
            #pragma unroll
            for (int tn = 0; tn < 4; ++tn)
                acc[tm][tn] = __builtin_amdgcn_mfma_f32_16x16x32_bf16(fa[tm], fb[tn], acc[tm][tn], 0, 0, 0);
        __syncthreads();
    }
    // bias + per-row sum/sumsq (16-lane shuffle, cross-wave via LDS), LN2, store
    float sumv[2][4], sqv[2][4];
    #pragma unroll
    for (int tm = 0; tm < 2; ++tm)
        #pragma unroll
        for (int r = 0; r < 4; ++r) {
            float s = 0.f, q = 0.f;
            #pragma unroll
            for (int tn = 0; tn < 4; ++tn) {
                float v = acc[tm][tn][r] + bias[wn * 64 + tn * 16 + fm];
                acc[tm][tn][r] = v;
                s += v; q += v * v;
            }
            #pragma unroll
            for (int off = 1; off < 16; off <<= 1) { s += __shfl_xor(s, off); q += __shfl_xor(q, off); }
            sumv[tm][r] = s; sqv[tm][r] = q;
        }
    if (fm == 0) {
        #pragma unroll
        for (int tm = 0; tm < 2; ++tm)
            #pragma unroll
            for (int r = 0; r < 4; ++r) {
                int row = wm * 32 + tm * 16 + fq * 4 + r;
                red[wn][0][row] = sumv[tm][r];
                red[wn][1][row] = sqv[tm][r];
            }
    }
    __syncthreads();
    #pragma unroll
    for (int tm = 0; tm < 2; ++tm)
        #pragma unroll
        for (int r = 0; r < 4; ++r) {
            int row = wm * 32 + tm * 16 + fq * 4 + r;
            int m = m0 + row;
            float s = red[0][0][row] + red[1][0][row];
            float q = red[0][1][row] + red[1][1][row];
            float mean = s * (1.0f / 128.0f);
            float var  = q * (1.0f / 128.0f) - mean * mean;
            float rstd = rsqrtf(var + 1e-5f);
            if (m < M) {
                #pragma unroll
                for (int tn = 0; tn < 4; ++tn) {
                    int nn = wn * 64 + tn * 16 + fm;
                    float o = (acc[tm][tn][r] - mean) * rstd * g[nn] + bta[nn];
                    Out[(size_t)m * 128 + nn] = bfr(o);
                }
            }
        }
}

// ---------------- MLP GEMM: 64x128 tile, LDS-staged, single-plane bf16 (R6) ----------------
// mode 1: GELU + bf16 out [M,N]; mode 3: fp32 scatter-remap out (fc2 -> y, N=128)
__global__ __launch_bounds__(256) void gemm_w(
    const unsigned short* __restrict__ A, const unsigned short* __restrict__ W,
    const float* __restrict__ bias,
    float* __restrict__ OutF, unsigned short* __restrict__ OutH,
    int M, int N, int K, int mode, int tbase)
{
    __shared__ __align__(16) unsigned short As[64 * 40];
    __shared__ __align__(16) unsigned short Ws[128 * 40];
    int tid = threadIdx.x;
    int wv = tid >> 6, ln = tid & 63;
    int wm = wv & 1, wn = wv >> 1;
    int fm = ln & 15, fq = ln >> 4;
    int m0 = blockIdx.y * 64, n0 = blockIdx.x * 128;
    int sr = tid >> 2, sk = (tid & 3) * 8;
    int arow = m0 + sr; if (arow >= M) arow = M - 1;
    const unsigned short* pA  = A + (size_t)arow * K + sk;
    const unsigned short* pW0 = W + (size_t)(n0 + sr) * K + sk;
    const unsigned short* pW1 = W + (size_t)(n0 + 64 + sr) * K + sk;
    int so = sr * 40 + sk;

    f4v acc[2][4] = {};
    s8v ra, rw0, rw1;
    #define LOADK(k0) do { \
        ra  = *reinterpret_cast<const s8v*>(pA  + (k0)); \
        rw0 = *reinterpret_cast<const s8v*>(pW0 + (k0)); \
        rw1 = *reinterpret_cast<const s8v*>(pW1 + (k0)); } while (0)
    LOADK(0);
    for (int k0 = 0; k0 < K; k0 += 32) {
        *reinterpret_cast<s8v*>(&As[so]) = ra;
        *reinterpret_cast<s8v*>(&Ws[so]) = rw0;
        *reinterpret_cast<s8v*>(&Ws[2560 + so]) = rw1;
        __syncthreads();
        if (k0 + 32 < K) LOADK(k0 + 32);        // prefetch next k-step
        s8v fa[2], fb[4];
        #pragma unroll
        for (int t = 0; t < 2; ++t)
            fa[t] = *reinterpret_cast<const s8v*>(&As[(wm * 32 + t * 16 + fm) * 40 + fq * 8]);
        #pragma unroll
        for (int t = 0; t < 4; ++t)
            fb[t] = *reinterpret_cast<const s8v*>(&Ws[(wn * 64 + t * 16 + fm) * 40 + fq * 8]);
        #pragma unroll
        for (int tm = 0; tm < 2; ++tm)
            #pragma unroll
            for (int tn = 0; tn < 4; ++tn)
                acc[tm][tn] = __builtin_amdgcn_mfma_f32_16x16x32_bf16(fa[tm], fb[tn], acc[tm][tn], 0, 0, 0);
        __syncthreads();
    }
    #undef LOADK

    #pragma unroll
    for (int tm = 0; tm < 2; ++tm)
        #pragma unroll
        for (int tn = 0; tn < 4; ++tn) {
            int col = n0 + wn * 64 + tn * 16 + fm;
            float bv = bias[col];
            #pragma unroll
            for (int r = 0; r < 4; ++r) {
                int m = m0 + wm * 32 + tm * 16 + fq * 4 + r;
                if (m >= M) continue;
                float v = acc[tm][tn][r] + bv;
                if (mode == 1) {
                    v = 0.5f * v * (1.0f + erff(v * 0.70710678118654752f));
                    OutH[(size_t)m * N + col] = bfr(v);
                } else {
                    int t = tbase + m;
                    int n = t / 49, l = t - n * 49;
                    int b = n >> 6, wh_ = (n >> 3) & 7, ww = n & 7;
                    int i = l / 7, jj = l - i * 7;
                    size_t orow = (size_t)((b * 56 + wh_ * 7 + i) * 56 + ww * 7 + jj);
                    OutF[orow * N + col] = v;
                }
            }
        }
}

extern "C" void kernel_launch(void* const* d_in, const int* in_sizes, int n_in,
                              void* d_out, int out_size, void* d_ws, size_t ws_size,
                              hipStream_t stream) {
    const float* x    = (const float*)d_in[0];
    const float* n1g  = (const float*)d_in[1];
    const float* n1b  = (const float*)d_in[2];
    const float* qkvw = (const float*)d_in[3];
    const float* qkvb = (const float*)d_in[4];
    const float* outw = (const float*)d_in[5];
    const float* outb = (const float*)d_in[6];
    const float* pe   = (const float*)d_in[7];
    const float* n2g  = (const float*)d_in[8];
    const float* n2b  = (const float*)d_in[9];
    const float* w1   = (const float*)d_in[10];
    const float* b1   = (const float*)d_in[11];
    const float* w2   = (const float*)d_in[12];
    const float* b2   = (const float*)d_in[13];
    float* y = (float*)d_out;

    // fixed overhead: 64 KB btab + 480 KB weight planes = 557056 B
    // per-window: QK 25088 + V 16384 + O 12544 + L 12544 + H 50176 = 116736 B
    size_t wpc = NWIN;
    while (wpc > 8 && 557056 + wpc * 116736ULL > ws_size) wpc >>= 1;
    const int nchunks = (int)(NWIN / wpc);
    const size_t rows = wpc * 49;

    char* ws = (char*)d_ws;
    float* btab = (float*)ws;                                    // 64 KB
    unsigned short* wpl = (unsigned short*)(ws + 65536);         // 491520 B of planes
    unsigned short* bufQK = (unsigned short*)(ws + 557056);      // rows*256
    unsigned short* bufV  = bufQK + rows * 256;                  // wpc*8192
    unsigned short* bufO  = bufV + wpc * 8192;                   // rows*128 (attn out)
    unsigned short* bufL  = bufO + rows * 128;                   // rows*128 (LN2 out)
    unsigned short* bufH  = bufL + rows * 128;                   // rows*512 (hidden)
    const int gy = (int)((rows + 63) / 64);

    presplit_kernel<<<768, 256, 0, stream>>>(qkvw, outw, w1, w2, wpl);
    bias_tab_kernel<<<1, 256, 0, stream>>>(pe, btab);

    for (int c = 0; c < nchunks; ++c) {
        int tbase = (int)(c * wpc * 49);
        // fused LN1 + QKV (3-term): x -> QK [rows,256] + V^T [wpc,128,64]
        ln_qkv<<<dim3(6, gy), 256, 0, stream>>>(
            x, n1g, n1b, wpl, qkvb, bufQK, bufV, (int)rows, tbase);
        // attention -> bf16 [rows,128]
        attn_mfma<<<(int)wpc, 256, 0, stream>>>(bufQK, bufV, btab, bufO);
        // proj + LN2 fused (LDS-staged single-plane W) -> bf16 [rows,128]
        proj_ln<<<gy, 256, 0, stream>>>(bufO, wpl + 98304, outb, n2g, n2b, bufL, (int)rows);
        // fc1 + GELU -> bf16 hidden [rows,512]
        gemm_w<<<dim3(4, gy), 256, 0, stream>>>(
            bufL, wpl + 114688, b1, nullptr, bufH, (int)rows, 512, 128, 1, 0);
        // fc2: hidden read once -> fp32 scatter to y
        gemm_w<<<dim3(1, gy), 256, 0, stream>>>(
            bufH, wpl + 180224, b2, y, nullptr, (int)rows, 128, 512, 3, tbase);
    }
}